// Round 2
// baseline (367.983 us; speedup 1.0000x reference)
//
#include <hip/hip_runtime.h>
#include <math.h>
#include <stdint.h>

#define N_PTS 1024
#define K_FPS 32

typedef unsigned long long u64;
typedef unsigned int u32;

__device__ __forceinline__ u64 shfl_xor_u64(u64 v, int mask) {
    return __shfl_xor(v, mask, 64);
}

__device__ __forceinline__ int imax2(int a, int b) { return a > b ? a : b; }

template<int CTRL, int RM>
__device__ __forceinline__ int dpp_upd(int v) {
    return __builtin_amdgcn_update_dpp(0, v, CTRL, RM, 0xf, true);
}

// partner value at lane^M (within wave), element-wise on u64
template<int M>
__device__ __forceinline__ u64 xshfl(u64 v) {
    if constexpr (M == 32) {
        return shfl_xor_u64(v, 32);
    } else {
        u32 lo = (u32)v, hi = (u32)(v >> 32);
        if constexpr (M == 1) {            // quad_perm [1,0,3,2] : lane^1
            lo = (u32)dpp_upd<0xB1, 0xf>((int)lo);
            hi = (u32)dpp_upd<0xB1, 0xf>((int)hi);
        } else if constexpr (M == 2) {     // quad_perm [2,3,0,1] : lane^2
            lo = (u32)dpp_upd<0x4E, 0xf>((int)lo);
            hi = (u32)dpp_upd<0x4E, 0xf>((int)hi);
        } else {                           // ds_swizzle xor, M in {4,8,16}
            constexpr int imm = (M << 10) | 0x1F;
            lo = (u32)__builtin_amdgcn_ds_swizzle((int)lo, imm);
            hi = (u32)__builtin_amdgcn_ds_swizzle((int)hi, imm);
        }
        return ((u64)hi << 32) | lo;
    }
}

// Element mapping: p = L*8 + r, L = threadIdx.x (0..127), r = 0..7.
// Intra-lane stage, j in {1,2,4}.
template<int J>
__device__ __forceinline__ void intra8(u64 key[8], int L, int k) {
    #pragma unroll
    for (int r = 0; r < 8; ++r) {
        if ((r & J) == 0) {
            const int r2 = r | J;
            int p = (L << 3) | r;
            bool up = ((p & k) == 0);
            u64 a = key[r], c = key[r2];
            bool sw = a < c;
            u64 lo2 = sw ? a : c;
            u64 hi2 = sw ? c : a;
            key[r]  = up ? lo2 : hi2;
            key[r2] = up ? hi2 : lo2;
        }
    }
}

// Cross-lane stage within a wave, j = 8*M, M in {1..32}; k >= 16.
template<int M>
__device__ __forceinline__ void cross8(u64 key[8], int L, int k) {
    bool low = ((L & M) == 0);
    bool up  = ((L & (k >> 3)) == 0);
    bool sel = (low == up);
    #pragma unroll
    for (int r = 0; r < 8; ++r) {
        u64 o = xshfl<M>(key[r]);
        key[r] = ((key[r] < o) == sel) ? key[r] : o;
    }
}

// ---------------------------------------------------------------------------
// MLP 32->16->8->1 + softplus for ONE point, evaluated per-lane.
// Deliberately OUTSIDE any contract(off) region: explicit contract(fast)
// reproduces the old mlp_kernel's v_fmac codegen (same accumulation order
// per output: i ascending), so results are bit-identical to the verified
// separate-kernel version. Weight addresses are wave-uniform -> s_load.
// ---------------------------------------------------------------------------
__device__ float mlp_point(const float* __restrict__ xr,
                           const float* __restrict__ W1, const float* __restrict__ b1,
                           const float* __restrict__ W2, const float* __restrict__ b2,
                           const float* __restrict__ W3, const float* __restrict__ b3)
{
#pragma clang fp contract(fast)
    float h1[16];
    #pragma unroll
    for (int j = 0; j < 16; ++j) h1[j] = b1[j];
    // transposed accumulation: per h1[j] the += chain is still i = 0..31
    // in ascending order -> identical bits to the j-outer/i-inner loop.
    #pragma unroll
    for (int i = 0; i < 32; i += 4) {
        float4 v = *(const float4*)(xr + i);
        float xv[4] = {v.x, v.y, v.z, v.w};
        #pragma unroll
        for (int q = 0; q < 4; ++q) {
            #pragma unroll
            for (int j = 0; j < 16; ++j)
                h1[j] += xv[q] * W1[(i + q) * 16 + j];
        }
    }
    #pragma unroll
    for (int j = 0; j < 16; ++j) h1[j] = fmaxf(h1[j], 0.0f);

    float h2[8];
    #pragma unroll
    for (int j = 0; j < 8; ++j) {
        float a = b2[j];
        #pragma unroll
        for (int i = 0; i < 16; ++i) a += h1[i] * W2[i * 8 + j];
        h2[j] = fmaxf(a, 0.0f);
    }
    float v = b3[0];
    #pragma unroll
    for (int i = 0; i < 8; ++i) v += h2[i] * W3[i];

    return fmaxf(v, 0.0f) + log1pf(expf(-fabsf(v)));
}

// ---------------------------------------------------------------------------
// Fused sort+FPS+MLP: TWO waves per submap (block=128), p = L*8 + r mapping.
// Bitonic 1024 (DPP/ds_swizzle/shfl cross stages); single cross-wave stage
// (j=512) via 4 KB LDS exchange, after which wave 1 retires. Wave 0 finishes
// the merge, runs FPS over ranks 0..511 (winner coords carried through the
// argmax tree + readlane broadcast -- no LDS on the serial chain), then
// lanes 0..31 evaluate the score MLP for their winner in-register.
// ---------------------------------------------------------------------------
__global__ __launch_bounds__(128) void sortfps_kernel(
    const float* __restrict__ pos,
    const float* __restrict__ x,
    const float* __restrict__ W1, const float* __restrict__ b1,
    const float* __restrict__ W2, const float* __restrict__ b2,
    const float* __restrict__ W3, const float* __restrict__ b3,
    float* __restrict__ out_w,
    float* __restrict__ out_idx,
    int B)
{
#pragma clang fp contract(off)
    const int t    = threadIdx.x;      // global element-lane L, 0..127
    const int lane = t & 63;
    const int wv   = t >> 6;
    const int b    = blockIdx.x;

    __shared__ __attribute__((aligned(16))) float spts[N_PTS * 3]; // 12 KB
    __shared__ u64 xch[512];                                        // 4 KB

    if (b >= B) return;

    const float* pb = pos + (size_t)b * N_PTS * 3;

    // ---- load 8 contiguous points/lane (96 B), stage to LDS ----
    float4 f4[6];
    {
        const float4* pb4 = (const float4*)pb + (size_t)t * 6;
        #pragma unroll
        for (int i = 0; i < 6; ++i) f4[i] = pb4[i];
        float4* sp4 = (float4*)spts + t * 6;
        #pragma unroll
        for (int i = 0; i < 6; ++i) sp4[i] = f4[i];
    }
    const float* f = (const float*)&f4[0];

    // ---- build keys: (bits(sqrt(x^2+y^2)) << 32) | p ----
    u64 key[8];
    #pragma unroll
    for (int r = 0; r < 8; ++r) {
        int p = (t << 3) | r;
        float xc = f[r * 3 + 0];
        float yc = f[r * 3 + 1];
        float xx = xc * xc, yy = yc * yc;
        float d = sqrtf(xx + yy);          // IEEE sqrt, matches np
        key[r] = ((u64)__float_as_uint(d) << 32) | (u32)p;
    }

    // ---- bitonic sort ascending over 1024 elements ----
    intra8<1>(key, t, 2);
    intra8<2>(key, t, 4);  intra8<1>(key, t, 4);
    intra8<4>(key, t, 8);  intra8<2>(key, t, 8);  intra8<1>(key, t, 8);

    cross8<1>(key, t, 16);
    intra8<4>(key, t, 16); intra8<2>(key, t, 16); intra8<1>(key, t, 16);

    cross8<2>(key, t, 32); cross8<1>(key, t, 32);
    intra8<4>(key, t, 32); intra8<2>(key, t, 32); intra8<1>(key, t, 32);

    cross8<4>(key, t, 64); cross8<2>(key, t, 64); cross8<1>(key, t, 64);
    intra8<4>(key, t, 64); intra8<2>(key, t, 64); intra8<1>(key, t, 64);

    cross8<8>(key, t, 128); cross8<4>(key, t, 128); cross8<2>(key, t, 128);
    cross8<1>(key, t, 128);
    intra8<4>(key, t, 128); intra8<2>(key, t, 128); intra8<1>(key, t, 128);

    cross8<16>(key, t, 256); cross8<8>(key, t, 256); cross8<4>(key, t, 256);
    cross8<2>(key, t, 256);  cross8<1>(key, t, 256);
    intra8<4>(key, t, 256); intra8<2>(key, t, 256); intra8<1>(key, t, 256);

    cross8<32>(key, t, 512); cross8<16>(key, t, 512); cross8<8>(key, t, 512);
    cross8<4>(key, t, 512);  cross8<2>(key, t, 512);  cross8<1>(key, t, 512);
    intra8<4>(key, t, 512); intra8<2>(key, t, 512); intra8<1>(key, t, 512);

    // ---- k=1024, j=512: cross-wave via LDS; merge is all-ascending so
    //      wave0 keeps min(own, partner); wave1's half is dead -> retire ----
    if (wv == 1) {
        #pragma unroll
        for (int r = 0; r < 8; ++r) xch[r * 64 + lane] = key[r];
    }
    __syncthreads();   // also covers spts visibility for the gather below
    if (wv == 1) return;

    #pragma unroll
    for (int r = 0; r < 8; ++r) {
        u64 o = xch[r * 64 + lane];
        key[r] = key[r] < o ? key[r] : o;
    }
    cross8<32>(key, t, 1024); cross8<16>(key, t, 1024); cross8<8>(key, t, 1024);
    cross8<4>(key, t, 1024);  cross8<2>(key, t, 1024);  cross8<1>(key, t, 1024);
    intra8<4>(key, t, 1024); intra8<2>(key, t, 1024); intra8<1>(key, t, 1024);

    // Ranks 0..511 (== jax.lax.top_k(-dist) order): lane L holds ranks L*8+r.

    // ---- gather selected coords from LDS ----
    float px[8], py[8], pz[8], pidx[8], mind[8];
    #pragma unroll
    for (int r = 0; r < 8; ++r) {
        int o = (int)(u32)key[r];
        const float* sp = &spts[o * 3];
        px[r] = sp[0]; py[r] = sp[1]; pz[r] = sp[2];
        pidx[r] = (float)o;
    }

    // ---- FPS ----
    float* ob = out_idx + (size_t)b * K_FPS;
    int o0 = __builtin_amdgcn_readfirstlane((int)(u32)key[0]);  // rank 0
    float wx = spts[o0 * 3], wy = spts[o0 * 3 + 1], wz = spts[o0 * 3 + 2];
    float acc = (float)o0;   // lane it accumulates winner of iteration it

    #pragma unroll
    for (int r = 0; r < 8; ++r) {
        float dx = px[r] - wx, dy = py[r] - wy, dz = pz[r] - wz;
        float u0 = dx * dx, u1 = dy * dy, u2 = dz * dz;
        mind[r] = (u0 + u1) + u2;          // np sequential axis sum
    }

    for (int it = 1; it < K_FPS; ++it) {
        // local argmax over r: 3-level tree carrying (v, idx, x, y, z);
        // strict > keeps smallest r.
        float v4[4], i4[4], x4[4], y4[4], z4[4];
        #pragma unroll
        for (int q = 0; q < 4; ++q) {
            bool g = mind[2 * q + 1] > mind[2 * q];
            v4[q] = g ? mind[2 * q + 1] : mind[2 * q];
            i4[q] = g ? pidx[2 * q + 1] : pidx[2 * q];
            x4[q] = g ? px[2 * q + 1] : px[2 * q];
            y4[q] = g ? py[2 * q + 1] : py[2 * q];
            z4[q] = g ? pz[2 * q + 1] : pz[2 * q];
        }
        bool s01 = v4[1] > v4[0];
        float va = s01 ? v4[1] : v4[0], ia = s01 ? i4[1] : i4[0];
        float xa = s01 ? x4[1] : x4[0], ya = s01 ? y4[1] : y4[0];
        float za = s01 ? z4[1] : z4[0];
        bool s23 = v4[3] > v4[2];
        float vb = s23 ? v4[3] : v4[2], ib = s23 ? i4[3] : i4[2];
        float xb = s23 ? x4[3] : x4[2], yb = s23 ? y4[3] : y4[2];
        float zb = s23 ? z4[3] : z4[2];
        bool sab = vb > va;
        float bv = sab ? vb : va, bi = sab ? ib : ia;
        float bx = sab ? xb : xa, by = sab ? yb : ya, bz = sab ? zb : za;

        // wave max via DPP (all values are non-negative float bit patterns,
        // so signed-int max == float max and the bound_ctrl 0-fill is safe)
        int bvi = __float_as_int(bv);
        int g = bvi;
        g = imax2(g, dpp_upd<0x111, 0xf>(g));   // row_shr:1
        g = imax2(g, dpp_upd<0x112, 0xf>(g));   // row_shr:2
        g = imax2(g, dpp_upd<0x114, 0xf>(g));   // row_shr:4
        g = imax2(g, dpp_upd<0x118, 0xf>(g));   // row_shr:8
        g = imax2(g, dpp_upd<0x142, 0xa>(g));   // row_bcast:15 -> rows 1,3
        g = imax2(g, dpp_upd<0x143, 0xc>(g));   // row_bcast:31 -> rows 2,3
        int gmax = __builtin_amdgcn_readlane(g, 63);

        u64 mask = __ballot(bvi == gmax);
        int W = __ffsll((unsigned long long)mask) - 1;  // smallest lane = smallest rank
        // broadcast winner payload straight from the winning lane's registers
        wx = __uint_as_float(__builtin_amdgcn_readlane(__float_as_uint(bx), W));
        wy = __uint_as_float(__builtin_amdgcn_readlane(__float_as_uint(by), W));
        wz = __uint_as_float(__builtin_amdgcn_readlane(__float_as_uint(bz), W));
        float wi = __uint_as_float(__builtin_amdgcn_readlane(__float_as_uint(bi), W));
        if (lane == it) acc = wi;

        #pragma unroll
        for (int r = 0; r < 8; ++r) {
            float dx = px[r] - wx, dy = py[r] - wy, dz = pz[r] - wz;
            float u0 = dx * dx, u1 = dy * dy, u2 = dz * dz;
            float d2 = (u0 + u1) + u2;
            mind[r] = fminf(mind[r], d2);
        }
    }

    // ---- outputs + fused MLP on the 32 winners ----
    if (lane < K_FPS) {
        ob[lane] = acc;                         // coalesced 128 B store
        int orig = (int)acc;
        const float* xr = x + ((size_t)b * N_PTS + (size_t)orig) * 32;
        float w = mlp_point(xr, W1, b1, W2, b2, W3, b3);
        out_w[(size_t)b * K_FPS + lane] = w;    // coalesced 128 B store
    }
}

extern "C" void kernel_launch(void* const* d_in, const int* in_sizes, int n_in,
                              void* d_out, int out_size, void* d_ws, size_t ws_size,
                              hipStream_t stream) {
    const float* x   = (const float*)d_in[0];
    const float* pos = (const float*)d_in[1];
    const float* W1 = (const float*)d_in[3];
    const float* b1 = (const float*)d_in[4];
    const float* W2 = (const float*)d_in[5];
    const float* b2 = (const float*)d_in[6];
    const float* W3 = (const float*)d_in[7];
    const float* b3 = (const float*)d_in[8];

    const int B = in_sizes[2] / N_PTS;              // 2048
    float* out_w = (float*)d_out;                   // [B*K_FPS]
    float* out_i = (float*)d_out + (size_t)B * K_FPS;

    sortfps_kernel<<<B, 128, 0, stream>>>(
        pos, x, W1, b1, W2, b2, W3, b3, out_w, out_i, B);
}

// Round 4
// 355.127 us; speedup vs baseline: 1.0362x; 1.0362x over previous
//
#include <hip/hip_runtime.h>
#include <math.h>
#include <stdint.h>

#define N_PTS 1024
#define K_FPS 32

typedef unsigned long long u64;
typedef unsigned int u32;
typedef unsigned int uint2v __attribute__((ext_vector_type(2)));

__device__ __forceinline__ int imax2(int a, int b) { return a > b ? a : b; }

template<int CTRL, int RM>
__device__ __forceinline__ int dpp_upd(int v) {
    return __builtin_amdgcn_update_dpp(0, v, CTRL, RM, 0xf, true);
}

// ---------------------------------------------------------------------------
// Cross-lane exchange: returns value held by lane^M, pure VALU on gfx950.
//  M=1,2 : quad_perm DPP
//  M=4,8 : row_shl/row_shr DPP pair + cndmask (in-row; boundary lanes are
//          never selected: for M=4, shl4 is chosen by lanes with (i&4)==0,
//          whose source i+4 stays in the 16-lane row; symmetrically shr4)
//  M=16  : v_permlane16_swap_b32: swaps ODD rows of vdst with EVEN rows of
//          vsrc. With both = x: new_vdst[odd-row lane i] = x[i-16],
//          new_vsrc[even-row lane i] = x[i+16]. So odd-row lanes take r.x,
//          even-row lanes take r.y.
//  M=32  : v_permlane32_swap_b32: swaps rows 2-3 of vdst with rows 0-1 of
//          vsrc. With both = x: new_vdst[i+32] = x[i], new_vsrc[i] = x[i+32].
//          So lanes >=32 take r.x, lanes <32 take r.y.
//          (Round-3 bug: selector was inverted -> every lane read itself ->
//          cross8<32> was a no-op -> missort. Fixed.)
// ---------------------------------------------------------------------------
template<int M>
__device__ __forceinline__ u32 xlane(u32 x, int lane) {
    if constexpr (M == 1) {
        return (u32)dpp_upd<0xB1, 0xf>((int)x);           // quad_perm [1,0,3,2]
    } else if constexpr (M == 2) {
        return (u32)dpp_upd<0x4E, 0xf>((int)x);           // quad_perm [2,3,0,1]
    } else if constexpr (M == 4) {
        u32 a = (u32)dpp_upd<0x104, 0xf>((int)x);         // row_shl:4  -> x[i+4]
        u32 b = (u32)dpp_upd<0x114, 0xf>((int)x);         // row_shr:4  -> x[i-4]
        return (lane & 4) ? b : a;
    } else if constexpr (M == 8) {
        u32 a = (u32)dpp_upd<0x108, 0xf>((int)x);         // row_shl:8  -> x[i+8]
        u32 b = (u32)dpp_upd<0x118, 0xf>((int)x);         // row_shr:8  -> x[i-8]
        return (lane & 8) ? b : a;
    } else if constexpr (M == 16) {
#if __has_builtin(__builtin_amdgcn_permlane16_swap)
        uint2v r = __builtin_amdgcn_permlane16_swap(x, x, false, false);
        return (lane & 16) ? r.x : r.y;
#else
        return (u32)__builtin_amdgcn_ds_swizzle((int)x, (16 << 10) | 0x1F);
#endif
    } else { // M == 32
#if __has_builtin(__builtin_amdgcn_permlane32_swap)
        uint2v r = __builtin_amdgcn_permlane32_swap(x, x, false, false);
        return (lane & 32) ? r.x : r.y;
#else
        return (u32)__shfl_xor((int)x, 32, 64);
#endif
    }
}

template<int M>
__device__ __forceinline__ u64 xshfl(u64 v, int lane) {
    u32 lo = xlane<M>((u32)v, lane);
    u32 hi = xlane<M>((u32)(v >> 32), lane);
    return ((u64)hi << 32) | lo;
}

// Element mapping: p = L*8 + r, L = threadIdx.x (0..127), r = 0..7.
// Intra-lane stage, j in {1,2,4}.
template<int J>
__device__ __forceinline__ void intra8(u64 key[8], int L, int k) {
    #pragma unroll
    for (int r = 0; r < 8; ++r) {
        if ((r & J) == 0) {
            const int r2 = r | J;
            int p = (L << 3) | r;
            bool up = ((p & k) == 0);
            u64 a = key[r], c = key[r2];
            bool sw = a < c;
            u64 lo2 = sw ? a : c;
            u64 hi2 = sw ? c : a;
            key[r]  = up ? lo2 : hi2;
            key[r2] = up ? hi2 : lo2;
        }
    }
}

// Cross-lane stage within a wave, j = 8*M, M in {1..32}; k >= 16.
template<int M>
__device__ __forceinline__ void cross8(u64 key[8], int L, int k) {
    const int lane = L & 63;
    bool low = ((L & M) == 0);
    bool up  = ((L & (k >> 3)) == 0);
    bool sel = (low == up);
    #pragma unroll
    for (int r = 0; r < 8; ++r) {
        u64 o = xshfl<M>(key[r], lane);
        key[r] = ((key[r] < o) == sel) ? key[r] : o;
    }
}

// ---------------------------------------------------------------------------
// MLP 32->16->8->1 + softplus for ONE point, evaluated per-lane.
// Deliberately OUTSIDE any contract(off) region: explicit contract(fast)
// reproduces the original mlp_kernel's v_fmac codegen (same accumulation
// order per output: i ascending), so results are bit-identical to the
// verified separate-kernel version. Weight addresses are wave-uniform.
// ---------------------------------------------------------------------------
__device__ float mlp_point(const float* __restrict__ xr,
                           const float* __restrict__ W1, const float* __restrict__ b1,
                           const float* __restrict__ W2, const float* __restrict__ b2,
                           const float* __restrict__ W3, const float* __restrict__ b3)
{
#pragma clang fp contract(fast)
    float h1[16];
    #pragma unroll
    for (int j = 0; j < 16; ++j) h1[j] = b1[j];
    // transposed accumulation: per h1[j] the += chain is still i = 0..31
    // ascending -> identical bits to the j-outer/i-inner loop.
    #pragma unroll
    for (int i = 0; i < 32; i += 4) {
        float4 v = *(const float4*)(xr + i);
        float xv[4] = {v.x, v.y, v.z, v.w};
        #pragma unroll
        for (int q = 0; q < 4; ++q) {
            #pragma unroll
            for (int j = 0; j < 16; ++j)
                h1[j] += xv[q] * W1[(i + q) * 16 + j];
        }
    }
    #pragma unroll
    for (int j = 0; j < 16; ++j) h1[j] = fmaxf(h1[j], 0.0f);

    float h2[8];
    #pragma unroll
    for (int j = 0; j < 8; ++j) {
        float a = b2[j];
        #pragma unroll
        for (int i = 0; i < 16; ++i) a += h1[i] * W2[i * 8 + j];
        h2[j] = fmaxf(a, 0.0f);
    }
    float v = b3[0];
    #pragma unroll
    for (int i = 0; i < 8; ++i) v += h2[i] * W3[i];

    return fmaxf(v, 0.0f) + log1pf(expf(-fabsf(v)));
}

// ---------------------------------------------------------------------------
// Fused sort+FPS+MLP: TWO waves per submap (block=128), p = L*8 + r mapping.
// Bitonic 1024 with ALL cross-lane exchanges in VALU (DPP quad_perm /
// row-shift pairs / permlane16_swap / permlane32_swap) -- the LDS pipe is
// idle during the sort. Single cross-wave stage (j=512) via a 4 KB LDS
// exchange, after which wave 1 retires. Wave 0 finishes the merge, runs
// FPS over ranks 0..511 (lean v+idx argmax carry, winner coords via
// uniform LDS read), then lanes 0..31 evaluate the score MLP in-register.
// ---------------------------------------------------------------------------
__global__ __launch_bounds__(128, 4) void sortfps_kernel(
    const float* __restrict__ pos,
    const float* __restrict__ x,
    const float* __restrict__ W1, const float* __restrict__ b1,
    const float* __restrict__ W2, const float* __restrict__ b2,
    const float* __restrict__ W3, const float* __restrict__ b3,
    float* __restrict__ out_w,
    float* __restrict__ out_idx,
    int B)
{
#pragma clang fp contract(off)
    const int t    = threadIdx.x;      // global element-lane L, 0..127
    const int lane = t & 63;
    const int wv   = t >> 6;
    const int b    = blockIdx.x;

    __shared__ __attribute__((aligned(16))) float spts[N_PTS * 3]; // 12 KB
    __shared__ u64 xch[512];                                        // 4 KB

    if (b >= B) return;

    const float* pb = pos + (size_t)b * N_PTS * 3;

    // ---- load 8 contiguous points/lane (96 B), stage to LDS ----
    float4 f4[6];
    {
        const float4* pb4 = (const float4*)pb + (size_t)t * 6;
        #pragma unroll
        for (int i = 0; i < 6; ++i) f4[i] = pb4[i];
        float4* sp4 = (float4*)spts + t * 6;
        #pragma unroll
        for (int i = 0; i < 6; ++i) sp4[i] = f4[i];
    }
    const float* f = (const float*)&f4[0];

    // ---- build keys: (bits(sqrt(x^2+y^2)) << 32) | p ----
    u64 key[8];
    #pragma unroll
    for (int r = 0; r < 8; ++r) {
        int p = (t << 3) | r;
        float xc = f[r * 3 + 0];
        float yc = f[r * 3 + 1];
        float xx = xc * xc, yy = yc * yc;
        float d = sqrtf(xx + yy);          // IEEE sqrt, matches np
        key[r] = ((u64)__float_as_uint(d) << 32) | (u32)p;
    }

    // ---- bitonic sort ascending over 1024 elements ----
    intra8<1>(key, t, 2);
    intra8<2>(key, t, 4);  intra8<1>(key, t, 4);
    intra8<4>(key, t, 8);  intra8<2>(key, t, 8);  intra8<1>(key, t, 8);

    cross8<1>(key, t, 16);
    intra8<4>(key, t, 16); intra8<2>(key, t, 16); intra8<1>(key, t, 16);

    cross8<2>(key, t, 32); cross8<1>(key, t, 32);
    intra8<4>(key, t, 32); intra8<2>(key, t, 32); intra8<1>(key, t, 32);

    cross8<4>(key, t, 64); cross8<2>(key, t, 64); cross8<1>(key, t, 64);
    intra8<4>(key, t, 64); intra8<2>(key, t, 64); intra8<1>(key, t, 64);

    cross8<8>(key, t, 128); cross8<4>(key, t, 128); cross8<2>(key, t, 128);
    cross8<1>(key, t, 128);
    intra8<4>(key, t, 128); intra8<2>(key, t, 128); intra8<1>(key, t, 128);

    cross8<16>(key, t, 256); cross8<8>(key, t, 256); cross8<4>(key, t, 256);
    cross8<2>(key, t, 256);  cross8<1>(key, t, 256);
    intra8<4>(key, t, 256); intra8<2>(key, t, 256); intra8<1>(key, t, 256);

    cross8<32>(key, t, 512); cross8<16>(key, t, 512); cross8<8>(key, t, 512);
    cross8<4>(key, t, 512);  cross8<2>(key, t, 512);  cross8<1>(key, t, 512);
    intra8<4>(key, t, 512); intra8<2>(key, t, 512); intra8<1>(key, t, 512);

    // ---- k=1024, j=512: cross-wave via LDS; merge is all-ascending so
    //      wave0 keeps min(own, partner); wave1's half is dead -> retire ----
    if (wv == 1) {
        #pragma unroll
        for (int r = 0; r < 8; ++r) xch[r * 64 + lane] = key[r];
    }
    __syncthreads();   // also covers spts visibility for the gather below
    if (wv == 1) return;

    #pragma unroll
    for (int r = 0; r < 8; ++r) {
        u64 o = xch[r * 64 + lane];
        key[r] = key[r] < o ? key[r] : o;
    }
    cross8<32>(key, t, 1024); cross8<16>(key, t, 1024); cross8<8>(key, t, 1024);
    cross8<4>(key, t, 1024);  cross8<2>(key, t, 1024);  cross8<1>(key, t, 1024);
    intra8<4>(key, t, 1024); intra8<2>(key, t, 1024); intra8<1>(key, t, 1024);

    // Ranks 0..511 (== jax.lax.top_k(-dist) order): lane L holds ranks L*8+r.

    // ---- gather selected coords from LDS ----
    float px[8], py[8], pz[8], pidx[8], mind[8];
    #pragma unroll
    for (int r = 0; r < 8; ++r) {
        int o = (int)(u32)key[r];
        const float* sp = &spts[o * 3];
        px[r] = sp[0]; py[r] = sp[1]; pz[r] = sp[2];
        pidx[r] = (float)o;
    }

    // ---- FPS ----
    int o0 = __builtin_amdgcn_readfirstlane((int)(u32)key[0]);  // rank 0
    float wx = spts[o0 * 3], wy = spts[o0 * 3 + 1], wz = spts[o0 * 3 + 2];
    float acc = (float)o0;   // lane it accumulates winner of iteration it

    #pragma unroll
    for (int r = 0; r < 8; ++r) {
        float dx = px[r] - wx, dy = py[r] - wy, dz = pz[r] - wz;
        float u0 = dx * dx, u1 = dy * dy, u2 = dz * dz;
        mind[r] = (u0 + u1) + u2;          // np sequential axis sum
    }

    for (int it = 1; it < K_FPS; ++it) {
        // local argmax over r: 3-level tree on (v, idx); strict > keeps
        // smallest r.
        float v4[4], i4[4];
        #pragma unroll
        for (int q = 0; q < 4; ++q) {
            bool g = mind[2 * q + 1] > mind[2 * q];
            v4[q] = g ? mind[2 * q + 1] : mind[2 * q];
            i4[q] = g ? pidx[2 * q + 1] : pidx[2 * q];
        }
        bool s01 = v4[1] > v4[0];
        float va = s01 ? v4[1] : v4[0], ia = s01 ? i4[1] : i4[0];
        bool s23 = v4[3] > v4[2];
        float vb = s23 ? v4[3] : v4[2], ib = s23 ? i4[3] : i4[2];
        bool sab = vb > va;
        float bv = sab ? vb : va, bi = sab ? ib : ia;

        // wave max via DPP (all values are non-negative float bit patterns,
        // so signed-int max == float max and the bound_ctrl 0-fill is safe)
        int bvi = __float_as_int(bv);
        int g = bvi;
        g = imax2(g, dpp_upd<0x111, 0xf>(g));   // row_shr:1
        g = imax2(g, dpp_upd<0x112, 0xf>(g));   // row_shr:2
        g = imax2(g, dpp_upd<0x114, 0xf>(g));   // row_shr:4
        g = imax2(g, dpp_upd<0x118, 0xf>(g));   // row_shr:8
        g = imax2(g, dpp_upd<0x142, 0xa>(g));   // row_bcast:15 -> rows 1,3
        g = imax2(g, dpp_upd<0x143, 0xc>(g));   // row_bcast:31 -> rows 2,3
        int gmax = __builtin_amdgcn_readlane(g, 63);

        u64 mask = __ballot(bvi == gmax);
        int W = __ffsll((unsigned long long)mask) - 1;  // smallest lane = smallest rank
        float wi = __uint_as_float(__builtin_amdgcn_readlane(__float_as_uint(bi), W));
        int wo = (int)wi;
        wx = spts[wo * 3]; wy = spts[wo * 3 + 1]; wz = spts[wo * 3 + 2];
        if (lane == it) acc = wi;

        #pragma unroll
        for (int r = 0; r < 8; ++r) {
            float dx = px[r] - wx, dy = py[r] - wy, dz = pz[r] - wz;
            float u0 = dx * dx, u1 = dy * dy, u2 = dz * dz;
            float d2 = (u0 + u1) + u2;
            mind[r] = fminf(mind[r], d2);
        }
    }

    // ---- outputs + fused MLP on the 32 winners ----
    if (lane < K_FPS) {
        out_idx[(size_t)b * K_FPS + lane] = acc;     // coalesced 128 B store
        int orig = (int)acc;
        const float* xr = x + ((size_t)b * N_PTS + (size_t)orig) * 32;
        float w = mlp_point(xr, W1, b1, W2, b2, W3, b3);
        out_w[(size_t)b * K_FPS + lane] = w;         // coalesced 128 B store
    }
}

extern "C" void kernel_launch(void* const* d_in, const int* in_sizes, int n_in,
                              void* d_out, int out_size, void* d_ws, size_t ws_size,
                              hipStream_t stream) {
    const float* x   = (const float*)d_in[0];
    const float* pos = (const float*)d_in[1];
    const float* W1 = (const float*)d_in[3];
    const float* b1 = (const float*)d_in[4];
    const float* W2 = (const float*)d_in[5];
    const float* b2 = (const float*)d_in[6];
    const float* W3 = (const float*)d_in[7];
    const float* b3 = (const float*)d_in[8];

    const int B = in_sizes[2] / N_PTS;              // 2048
    float* out_w = (float*)d_out;                   // [B*K_FPS]
    float* out_i = (float*)d_out + (size_t)B * K_FPS;

    sortfps_kernel<<<B, 128, 0, stream>>>(
        pos, x, W1, b1, W2, b2, W3, b3, out_w, out_i, B);
}